// Round 1
// 482.136 us; speedup vs baseline: 1.0463x; 1.0463x over previous
//
#include <hip/hip_runtime.h>
#include <hip/hip_bf16.h>
#include <hip/hip_fp16.h>

#define N_NODES 10000
#define N_PAIRS 200000
#define NFEAT 384
#define FH 128
#define SPH 15

typedef __bf16 bf16x8 __attribute__((ext_vector_type(8)));
typedef _Float16 half8 __attribute__((ext_vector_type(8)));
typedef float f32x4 __attribute__((ext_vector_type(4)));

// q[n, h*128+g] = sum_f x[n, h*128+f] * Wq[h, g, f]   (and same for k)
// One block = 16 nodes x 1 head; f32 inputs converted to bf16 in-registers.
// 4 waves x 4 tasks: task = (g-tile 0..7) x (q|k).
// MFMA 16x16x32 bf16: A[m=lane&15][k=quad*8+j], B[k=quad*8+j][n=lane&15],
// D: col=lane&15, row=quad*4+reg  (verified gfx950 mapping).
// Outputs stored as fp16 (11-bit mantissa: adds <0.03% rel error vs fp32,
// halves the gather traffic in pair_kernel).
__device__ inline bf16x8 cvt8(const float* __restrict__ p) {
    float4 lo = *(const float4*)p;
    float4 hi = *(const float4*)(p + 4);
    bf16x8 r;
    r[0] = (__bf16)lo.x; r[1] = (__bf16)lo.y; r[2] = (__bf16)lo.z; r[3] = (__bf16)lo.w;
    r[4] = (__bf16)hi.x; r[5] = (__bf16)hi.y; r[6] = (__bf16)hi.z; r[7] = (__bf16)hi.w;
    return r;
}

__global__ __launch_bounds__(256) void qk_gemm_kernel(
        const float* __restrict__ x,
        const float* __restrict__ Wq,
        const float* __restrict__ Wk,
        _Float16* __restrict__ q, _Float16* __restrict__ k) {
    const int head = blockIdx.y;
    const int node0 = blockIdx.x * 16;
    const int wave = threadIdx.x >> 6;
    const int lane = threadIdx.x & 63;
    const int mrow = lane & 15;   // A row (node) / B row (g)
    const int quad = lane >> 4;   // 0..3
    const float* xrow = x + (size_t)(node0 + mrow) * NFEAT + head * FH + quad * 8;
    // A fragment (16 nodes x 128 k) converted once, reused for all 16 tasks
    bf16x8 afrag[4];
#pragma unroll
    for (int t = 0; t < 4; ++t) afrag[t] = cvt8(xrow + t * 32);

    for (int task = wave; task < 16; task += 4) {
        const int mat = task & 1;
        const int g0 = (task >> 1) * 16;
        const float* Wrow =
            (mat ? Wk : Wq) + (size_t)head * FH * FH + (size_t)(g0 + mrow) * FH + quad * 8;
        f32x4 acc = {0.f, 0.f, 0.f, 0.f};
#pragma unroll
        for (int t = 0; t < 4; ++t) {
            bf16x8 b = cvt8(Wrow + t * 32);
            acc = __builtin_amdgcn_mfma_f32_16x16x32_bf16(afrag[t], b, acc, 0, 0, 0);
        }
        _Float16* dst = mat ? k : q;
        const int g = g0 + mrow;
#pragma unroll
        for (int r = 0; r < 4; ++r) {
            const int node = node0 + quad * 4 + r;
            dst[(size_t)node * NFEAT + head * FH + g] = (_Float16)acc[r];
        }
    }
}

// 4 pairs per wave, 16 lanes per pair. Lane `sub` owns 8 feats/head.
// alpha[h] = (sum_f q[i,h,f]*w[e,h,f]*k[j,h,f]) / sqrt(128) * (phi_r[e]+phi_chi[e])
// then subs 0..14 of each group scatter alpha_rep[c]*sph[e,c] into out[i,c].
// q/k are fp16 (cached, reused ~20x -> temporal loads); w_ij/sph/phi are
// single-use streams -> non-temporal so they don't evict the q/k working set.
__global__ __launch_bounds__(256) void pair_kernel(
        const _Float16* __restrict__ q, const _Float16* __restrict__ kk,
        const float* __restrict__ w_ij, const float* __restrict__ sph,
        const int* __restrict__ idx_i, const int* __restrict__ idx_j,
        const float* __restrict__ phi_r, const float* __restrict__ phi_chi,
        float* __restrict__ out) {
    const int lane = threadIdx.x & 63;
    const int sub = lane & 15;   // lane within pair-group
    const int grp = lane >> 4;   // which of 4 pairs in this wave
    const int wid = blockIdx.x * (blockDim.x >> 6) + (threadIdx.x >> 6);
    const int nw = gridDim.x * (blockDim.x >> 6);
    for (int base = wid * 4; base < N_PAIRS; base += nw * 4) {
        const int e = base + grp;
        if (e < N_PAIRS) {
            const int i = idx_i[e];
            const int j = idx_j[e];
            const _Float16* qr = q + (size_t)i * NFEAT;
            const _Float16* kr = kk + (size_t)j * NFEAT;
            const float* wr = w_ij + (size_t)e * NFEAT;
            float dot[3];
#pragma unroll
            for (int h = 0; h < 3; ++h) {
                const int f = h * FH + sub * 8;
                half8 qv = *(const half8*)(qr + f);
                half8 kv = *(const half8*)(kr + f);
                f32x4 wa = __builtin_nontemporal_load((const f32x4*)(wr + f));
                f32x4 wb = __builtin_nontemporal_load((const f32x4*)(wr + f + 4));
                float p = 0.f;
#pragma unroll
                for (int u = 0; u < 4; ++u) {
                    p = fmaf((float)qv[u] * wa[u], (float)kv[u], p);
                    p = fmaf((float)qv[u + 4] * wb[u], (float)kv[u + 4], p);
                }
                // reduce across the 16-lane group
#pragma unroll
                for (int off = 8; off; off >>= 1) p += __shfl_xor(p, off, 16);
                dot[h] = p;
            }
            const float pr = __builtin_nontemporal_load(phi_r + e);
            const float pc = __builtin_nontemporal_load(phi_chi + e);
            const float scale = (pr + pc) * 0.088388347648318447f;  // 1/sqrt(128)
            if (sub < SPH) {
                const int h = (sub < 3) ? 0 : (sub < 8 ? 1 : 2);
                const float s = __builtin_nontemporal_load(sph + (size_t)e * SPH + sub);
                const float val = dot[h] * scale * s;
                unsafeAtomicAdd(&out[(size_t)i * SPH + sub], val);
            }
        }
    }
}

extern "C" void kernel_launch(void* const* d_in, const int* in_sizes, int n_in,
                              void* d_out, int out_size, void* d_ws, size_t ws_size,
                              hipStream_t stream) {
    // inputs: 0 chi (unused), 1 sph_ij, 2 x, 3 w_ij, 4 idx_i, 5 phi_r_cut,
    //         6 phi_chi_cut, 7 idx_j, 8 Wq, 9 Wk
    const float* sph     = (const float*)d_in[1];
    const float* x       = (const float*)d_in[2];
    const float* w_ij    = (const float*)d_in[3];
    const int*   idx_i   = (const int*)d_in[4];
    const float* phi_r   = (const float*)d_in[5];
    const float* phi_chi = (const float*)d_in[6];
    const int*   idx_j   = (const int*)d_in[7];
    const float* Wq      = (const float*)d_in[8];
    const float* Wk      = (const float*)d_in[9];
    float* out = (float*)d_out;

    // workspace layout: q (7.68 MB fp16) + k (7.68 MB fp16)
    char* ws = (char*)d_ws;
    _Float16* qws = (_Float16*)ws;
    _Float16* kws = (_Float16*)(ws + 7680000);

    hipMemsetAsync(d_out, 0, (size_t)out_size * sizeof(float), stream);

    qk_gemm_kernel<<<dim3(N_NODES / 16, 3), 256, 0, stream>>>(x, Wq, Wk, qws, kws);

    pair_kernel<<<2048, 256, 0, stream>>>(qws, kws, w_ij, sph, idx_i, idx_j,
                                          phi_r, phi_chi, out);
}